// Round 1
// baseline (894.167 us; speedup 1.0000x reference)
//
#include <hip/hip_runtime.h>

// Problem constants (fixed by the reference)
#define N 2048
#define D 256
#define C 768          // 3*D
#define K2 512         // 2*D (concat [emb | msg])
#define V 2
#define L 16
#define NSTATE 15      // states S_0..S_14 (S_15 provably unused: step-15 mask is empty)
#define MAXM 2048      // worst-case masked places per (variant, step)
#define KC 32          // k-chunk rows of W staged in LDS

// ---------------------------------------------------------------------------
// k_init: zero pi / fillpos / mcnt, copy embeddings -> states[0],
//         pack Wcomb = [W_self ; W_nbr]  (Wcomb[k][c], k in [0,512))
// ---------------------------------------------------------------------------
__global__ __launch_bounds__(256) void k_init(
    const float* __restrict__ emb, const float* __restrict__ Ws,
    const float* __restrict__ Wn, float* __restrict__ states0,
    float* __restrict__ Wcomb, float* __restrict__ pi,
    int* __restrict__ fillpos, int* __restrict__ mcnt) {
  size_t i = (size_t)blockIdx.x * 256 + threadIdx.x;
  size_t stride = (size_t)gridDim.x * 256;
  for (size_t x = i; x < (size_t)N * D; x += stride) states0[x] = emb[x];
  for (size_t x = i; x < (size_t)D * D; x += stride) {
    Wcomb[x] = Ws[x];
    Wcomb[(size_t)D * D + x] = Wn[x];
  }
  for (size_t x = i; x < (size_t)V * N * C; x += stride) pi[x] = 0.f;
  for (size_t x = i; x < N; x += stride) fillpos[x] = 0;
  for (size_t x = i; x < V * L; x += stride) mcnt[x] = 0;
}

// ---------------------------------------------------------------------------
// CSR build over edge_index grouped by dst (segment_sum semantics, keeps
// edge multiplicity).  ei[0..E) = src, ei[E..2E) = dst.
// ---------------------------------------------------------------------------
__global__ void k_deg(const int* __restrict__ ei, int* __restrict__ fillpos, int E) {
  int e = blockIdx.x * 256 + threadIdx.x;
  if (e < E) atomicAdd(&fillpos[ei[E + e]], 1);
}

__global__ __launch_bounds__(256) void k_scan(int* __restrict__ fillpos,
                                              int* __restrict__ row_ptr) {
  __shared__ int part[256];
  __shared__ int base[257];
  int t = threadIdx.x;
  int v[8];
  int s = 0;
  for (int j = 0; j < 8; j++) { v[j] = fillpos[t * 8 + j]; s += v[j]; }
  part[t] = s;
  __syncthreads();
  if (t == 0) {
    int acc = 0;
    for (int q = 0; q < 256; q++) { base[q] = acc; acc += part[q]; }
    base[256] = acc;
  }
  __syncthreads();
  int acc = base[t];
  for (int j = 0; j < 8; j++) {
    row_ptr[t * 8 + j] = acc;
    fillpos[t * 8 + j] = acc;   // reset to row start for k_fill
    acc += v[j];
  }
  if (t == 255) row_ptr[N] = base[256];
}

__global__ void k_fill(const int* __restrict__ ei, int* __restrict__ fillpos,
                       int* __restrict__ csr_src, int E) {
  int e = blockIdx.x * 256 + threadIdx.x;
  if (e < E) {
    int dst = ei[E + e];
    int pos = atomicAdd(&fillpos[dst], 1);
    csr_src[pos] = ei[e];
  }
}

// ---------------------------------------------------------------------------
// k_meta: per (variant, step): has flag, distinct suffix list (tlist), and
// compacted masked-place list (mlist).  All emb-independent.
// ---------------------------------------------------------------------------
__global__ __launch_bounds__(256) void k_meta(
    const int* __restrict__ adj, const int* __restrict__ variants,
    int* __restrict__ hasA, int* __restrict__ tcntA, int* __restrict__ tlistA,
    int* __restrict__ mcntA, int* __restrict__ mlistA) {
  __shared__ int sh_has;
  __shared__ int sh_tl[L];
  __shared__ int sh_tc;
  int vi = blockIdx.x;
  int v = vi / L, i = vi % L;
  int t = threadIdx.x;
  int a = variants[vi];
  if (t == 0) {
    sh_has = 0;
    int cnt = 0;
    for (int j = i + 1; j < L; j++) {   // distinct nodes in acts[i+1:]
      int x = variants[v * L + j];
      bool dup = false;
      for (int q = 0; q < cnt; q++) if (sh_tl[q] == x) dup = true;
      if (!dup) sh_tl[cnt++] = x;
    }
    sh_tc = cnt;
  }
  __syncthreads();
  int any = 0;
  for (int p = t; p < N; p += 256) any |= (adj[(size_t)a * N + p] != 0);
  if (any) atomicOr(&sh_has, 1);
  __syncthreads();
  int hasv = sh_has, tc = sh_tc;
  if (t == 0) {
    hasA[vi] = hasv;
    tcntA[vi] = tc;
    for (int q = 0; q < tc; q++) tlistA[vi * L + q] = sh_tl[q];
  }
  if (hasv) {
    for (int p = t; p < N; p += 256) {
      if (adj[(size_t)a * N + p] != 0) {            // follower of a
        int dc = 0;
        for (int q = 0; q < tc; q++) dc |= (adj[(size_t)p * N + sh_tl[q]] != 0);
        if (dc) {                                   // has >=1 later destination
          int slot = atomicAdd(&mcntA[vi], 1);
          mlistA[vi * MAXM + slot] = p;
        }
      }
    }
  }
}

// ---------------------------------------------------------------------------
// k_enc: one encoder application  next = relu([prev | msg(prev)] @ Wcomb + b)
// grid 256 blocks x 256 threads, 8 rows/block, thread tile 2 rows x 4 cols.
// msg gathered per-block via CSR (wave w owns rows 2w, 2w+1 -> matches the
// matmul row assignment).  W staged through LDS in KC-row chunks; A-operand
// reads are wave-uniform LDS broadcasts.
// ---------------------------------------------------------------------------
__global__ __launch_bounds__(256) void k_enc(
    const float* __restrict__ prev, float* __restrict__ next,
    const float* __restrict__ Wc, const float* __restrict__ bias,
    const int* __restrict__ row_ptr, const int* __restrict__ csr_src) {
  __shared__ float At[8][K2 + 4];
  __shared__ float Wch[KC][D + 4];
  const int tid = threadIdx.x;
  const int wave = tid >> 6, lane = tid & 63;
  const int r0 = blockIdx.x * 8;

  // stage self part: At[r][0..255] = prev[r0+r]
  for (int x = tid; x < 8 * (D / 4); x += 256) {
    int r = x >> 6, c4 = x & 63;
    float4 vv = ((const float4*)(prev + (size_t)(r0 + r) * D))[c4];
    *(float4*)&At[r][c4 * 4] = vv;
  }
  // msg part: At[r][256..511] = sum over in-edges of prev[src]
  for (int rr = wave * 2; rr < wave * 2 + 2; rr++) {
    float4 acc = {0.f, 0.f, 0.f, 0.f};
    int e0 = row_ptr[r0 + rr], e1 = row_ptr[r0 + rr + 1];
    for (int e = e0; e < e1; e++) {
      const float4* srow = (const float4*)(prev + (size_t)csr_src[e] * D);
      float4 xv = srow[lane];
      acc.x += xv.x; acc.y += xv.y; acc.z += xv.z; acc.w += xv.w;
    }
    *(float4*)&At[rr][D + lane * 4] = acc;
  }

  float acc0[4] = {0.f, 0.f, 0.f, 0.f};
  float acc1[4] = {0.f, 0.f, 0.f, 0.f};
  const int rA = wave * 2, rB = rA + 1, c0 = lane * 4;

  for (int kc = 0; kc < K2; kc += KC) {
    __syncthreads();  // At complete (first iter) / prior Wch reads done
    for (int x = tid; x < KC * (D / 4); x += 256) {
      int kk = x >> 6, c4 = x & 63;
      float4 vv = ((const float4*)(Wc + (size_t)(kc + kk) * D))[c4];
      *(float4*)&Wch[kk][c4 * 4] = vv;
    }
    __syncthreads();
#pragma unroll 4
    for (int k = 0; k < KC; k++) {
      float a0 = At[rA][kc + k];       // wave-uniform -> LDS broadcast
      float a1 = At[rB][kc + k];
      float4 w = *(const float4*)&Wch[k][c0];
      acc0[0] += a0 * w.x; acc0[1] += a0 * w.y; acc0[2] += a0 * w.z; acc0[3] += a0 * w.w;
      acc1[0] += a1 * w.x; acc1[1] += a1 * w.y; acc1[2] += a1 * w.z; acc1[3] += a1 * w.w;
    }
  }

  float4 bv = *(const float4*)(bias + c0);
  float4 o0, o1;
  o0.x = fmaxf(acc0[0] + bv.x, 0.f); o0.y = fmaxf(acc0[1] + bv.y, 0.f);
  o0.z = fmaxf(acc0[2] + bv.z, 0.f); o0.w = fmaxf(acc0[3] + bv.w, 0.f);
  o1.x = fmaxf(acc1[0] + bv.x, 0.f); o1.y = fmaxf(acc1[1] + bv.y, 0.f);
  o1.z = fmaxf(acc1[2] + bv.z, 0.f); o1.w = fmaxf(acc1[3] + bv.w, 0.f);
  *(float4*)(next + (size_t)(r0 + rA) * D + c0) = o0;
  *(float4*)(next + (size_t)(r0 + rB) * D + c0) = o1;
}

// ---------------------------------------------------------------------------
// k_pi: replay the sparse pi/summary recurrence for both variants against the
// stored encoder powers.  6 blocks: (variant, col-group of 256).  Each thread
// owns one column c of [0,768) -- the whole recurrence is column-independent,
// summary lives in a register.
// ---------------------------------------------------------------------------
__global__ __launch_bounds__(256) void k_pi(
    const float* __restrict__ states, float* __restrict__ pi,
    const int* __restrict__ adj, const int* __restrict__ variants,
    const int* __restrict__ hasA, const int* __restrict__ tcntA,
    const int* __restrict__ tlistA, const int* __restrict__ mcntA,
    const int* __restrict__ mlistA) {
  int v = blockIdx.x / 3, cg = blockIdx.x % 3;
  int c = cg * 256 + threadIdx.x;      // 0..767
  float* piv = pi + (size_t)v * N * C;
  float summary = 0.f;
  int k = 0;
  for (int i = 0; i < L; i++) {
    int vi = v * L + i;
    const float* embS = states + (size_t)(k < NSTATE ? k : NSTATE - 1) * N * D;
    int a = variants[vi];
    int mc = mcntA[vi];
    int tc = tcntA[vi];
    // phase A: pi[p] += cat(p) = [emb[p], emb[a], dst_all[p]]
    for (int m = 0; m < mc; m++) {
      int p = mlistA[vi * MAXM + m];
      float catv;
      if (c < D) {
        catv = embS[(size_t)p * D + c];
      } else if (c < 2 * D) {
        catv = embS[(size_t)a * D + (c - D)];
      } else {
        float s = 0.f;
        for (int q = 0; q < tc; q++) {
          int t2 = tlistA[vi * L + q];
          if (adj[(size_t)p * N + t2] != 0) s += embS[(size_t)t2 * D + (c - 2 * D)];
        }
        catv = s;
      }
      piv[(size_t)p * C + c] += catv;
    }
    // phase B: summary += sum of masked pi rows (post phase A)
    float sacc = 0.f;
    for (int m = 0; m < mc; m++) {
      int p = mlistA[vi * MAXM + m];
      sacc += piv[(size_t)p * C + c];
    }
    summary += sacc;
    // phase C: pi[p] += summary (new)
    for (int m = 0; m < mc; m++) {
      int p = mlistA[vi * MAXM + m];
      piv[(size_t)p * C + c] += summary;
    }
    if (hasA[vi]) k++;   // advance encoder power only when has
  }
}

// ---------------------------------------------------------------------------
// k_out: d_out = pi[variant 0] + pi[variant 1]
// ---------------------------------------------------------------------------
__global__ void k_out(const float* __restrict__ pi, float* __restrict__ out) {
  size_t i = (size_t)blockIdx.x * 256 + threadIdx.x;
  size_t n4 = (size_t)N * C / 4;
  if (i < n4) {
    float4 a = ((const float4*)pi)[i];
    float4 b = ((const float4*)(pi + (size_t)N * C))[i];
    float4 o = {a.x + b.x, a.y + b.y, a.z + b.z, a.w + b.w};
    ((float4*)out)[i] = o;
  }
}

// ---------------------------------------------------------------------------
extern "C" void kernel_launch(void* const* d_in, const int* in_sizes, int n_in,
                              void* d_out, int out_size, void* d_ws, size_t ws_size,
                              hipStream_t stream) {
  const float* emb      = (const float*)d_in[0];
  const float* Ws       = (const float*)d_in[1];
  const float* Wn       = (const float*)d_in[2];
  const float* bias     = (const float*)d_in[3];
  const int*   variants = (const int*)d_in[4];
  const int*   adj      = (const int*)d_in[5];
  const int*   ei       = (const int*)d_in[6];
  const int    E        = in_sizes[6] / 2;

  float* ws      = (float*)d_ws;
  float* states  = ws;                                   // NSTATE * N * D
  float* Wcomb   = states + (size_t)NSTATE * N * D;      // K2 * D
  float* pi      = Wcomb + (size_t)K2 * D;               // V * N * C
  int*   row_ptr = (int*)(pi + (size_t)V * N * C);       // N+1
  int*   fillpos = row_ptr + (N + 1);                    // N
  int*   csr_src = fillpos + N;                          // E
  int*   hasA    = csr_src + E;                          // V*L
  int*   tcntA   = hasA + V * L;                         // V*L
  int*   tlistA  = tcntA + V * L;                        // V*L*L
  int*   mcntA   = tlistA + V * L * L;                   // V*L
  int*   mlistA  = mcntA + V * L;                        // V*L*MAXM

  k_init<<<1024, 256, 0, stream>>>(emb, Ws, Wn, states, Wcomb, pi, fillpos, mcntA);
  k_deg<<<(E + 255) / 256, 256, 0, stream>>>(ei, fillpos, E);
  k_scan<<<1, 256, 0, stream>>>(fillpos, row_ptr);
  k_fill<<<(E + 255) / 256, 256, 0, stream>>>(ei, fillpos, csr_src, E);
  k_meta<<<V * L, 256, 0, stream>>>(adj, variants, hasA, tcntA, tlistA, mcntA, mlistA);
  for (int s = 0; s < NSTATE - 1; s++)   // 14 encoder applications
    k_enc<<<N / 8, 256, 0, stream>>>(states + (size_t)s * N * D,
                                     states + (size_t)(s + 1) * N * D,
                                     Wcomb, bias, row_ptr, csr_src);
  k_pi<<<V * 3, 256, 0, stream>>>(states, pi, adj, variants, hasA, tcntA,
                                  tlistA, mcntA, mlistA);
  k_out<<<(N * C / 4 + 255) / 256, 256, 0, stream>>>(pi, (float*)d_out);
}

// Round 2
// 514.254 us; speedup vs baseline: 1.7388x; 1.7388x over previous
//
#include <hip/hip_runtime.h>

// Problem constants (fixed by the reference)
#define N 2048
#define D 256
#define C 768          // 3*D
#define K2 512         // 2*D (concat [emb | msg])
#define V 2
#define L 16
#define NSTATE 15      // S_0..S_14 (step-15 mask provably empty)
#define MAXM 2048

typedef __attribute__((ext_vector_type(8))) short bf16x8;
typedef __attribute__((ext_vector_type(4))) float f32x4;

__device__ __forceinline__ ushort bf16_rn(float x) {
  unsigned u = __float_as_uint(x);
  u += 0x7FFFu + ((u >> 16) & 1u);
  return (ushort)(u >> 16);
}
__device__ __forceinline__ float bf16_f(ushort h) {
  return __uint_as_float(((unsigned)h) << 16);
}

// ---------------------------------------------------------------------------
// k_init: states0 = emb; A0 self-half bf16 split; Wt = [W_self;W_nbr]^T split;
// zero pi / fillpos / mcnt.
// ---------------------------------------------------------------------------
__global__ __launch_bounds__(256) void k_init(
    const float* __restrict__ emb, const float* __restrict__ Ws,
    const float* __restrict__ Wn, float* __restrict__ states0,
    ushort* __restrict__ WtHi, ushort* __restrict__ WtLo,
    ushort* __restrict__ A0hi, ushort* __restrict__ A0lo,
    float* __restrict__ pi, int* __restrict__ fillpos, int* __restrict__ mcnt) {
  size_t i = (size_t)blockIdx.x * 256 + threadIdx.x;
  size_t stride = (size_t)gridDim.x * 256;
  for (size_t x = i; x < (size_t)N * D; x += stride) {
    float v = emb[x];
    states0[x] = v;
    ushort h = bf16_rn(v);
    ushort l = bf16_rn(v - bf16_f(h));
    size_t r = x >> 8, cc = x & 255;
    A0hi[r * K2 + cc] = h;
    A0lo[r * K2 + cc] = l;
  }
  for (size_t x = i; x < (size_t)D * K2; x += stride) {
    size_t cc = x >> 9, k = x & 511;  // x = cc*512 + k  (Wt[n=cc][k])
    float v = (k < D) ? Ws[k * D + cc] : Wn[(k - D) * D + cc];
    ushort h = bf16_rn(v);
    WtHi[x] = h;
    WtLo[x] = bf16_rn(v - bf16_f(h));
  }
  for (size_t x = i; x < (size_t)V * N * C; x += stride) pi[x] = 0.f;
  for (size_t x = i; x < N; x += stride) fillpos[x] = 0;
  for (size_t x = i; x < V * L; x += stride) mcnt[x] = 0;
}

// ---------------------------------------------------------------------------
// CSR build (by dst, keeps multiplicity).  ei[0..E)=src, ei[E..2E)=dst.
// ---------------------------------------------------------------------------
__global__ void k_deg(const int* __restrict__ ei, int* __restrict__ fillpos, int E) {
  int e = blockIdx.x * 256 + threadIdx.x;
  if (e < E) atomicAdd(&fillpos[ei[E + e]], 1);
}

__global__ __launch_bounds__(256) void k_scan(int* __restrict__ fillpos,
                                              int* __restrict__ row_ptr) {
  __shared__ int part[256];
  __shared__ int base[257];
  int t = threadIdx.x;
  int v[8];
  int s = 0;
  for (int j = 0; j < 8; j++) { v[j] = fillpos[t * 8 + j]; s += v[j]; }
  part[t] = s;
  __syncthreads();
  if (t == 0) {
    int acc = 0;
    for (int q = 0; q < 256; q++) { base[q] = acc; acc += part[q]; }
    base[256] = acc;
  }
  __syncthreads();
  int acc = base[t];
  for (int j = 0; j < 8; j++) {
    row_ptr[t * 8 + j] = acc;
    fillpos[t * 8 + j] = acc;
    acc += v[j];
  }
  if (t == 255) row_ptr[N] = base[256];
}

__global__ void k_fill(const int* __restrict__ ei, int* __restrict__ fillpos,
                       int* __restrict__ csr_src, int E) {
  int e = blockIdx.x * 256 + threadIdx.x;
  if (e < E) {
    int dst = ei[E + e];
    int pos = atomicAdd(&fillpos[dst], 1);
    csr_src[pos] = ei[e];
  }
}

// ---------------------------------------------------------------------------
// k_meta: per (variant, step): has flag, distinct suffix list, compacted
// masked-place list + per-place destination bitmask (over tlist indices).
// ---------------------------------------------------------------------------
__global__ __launch_bounds__(256) void k_meta(
    const int* __restrict__ adj, const int* __restrict__ variants,
    int* __restrict__ hasA, int* __restrict__ tcntA, int* __restrict__ tlistA,
    int* __restrict__ mcntA, int* __restrict__ mlistA, unsigned* __restrict__ mmaskA) {
  __shared__ int sh_has;
  __shared__ int sh_tl[L];
  __shared__ int sh_tc;
  int vi = blockIdx.x;
  int v = vi / L, i = vi % L;
  int t = threadIdx.x;
  int a = variants[vi];
  if (t == 0) {
    sh_has = 0;
    int cnt = 0;
    for (int j = i + 1; j < L; j++) {
      int x = variants[v * L + j];
      bool dup = false;
      for (int q = 0; q < cnt; q++) if (sh_tl[q] == x) dup = true;
      if (!dup) sh_tl[cnt++] = x;
    }
    sh_tc = cnt;
  }
  __syncthreads();
  int any = 0;
  for (int p = t; p < N; p += 256) any |= (adj[(size_t)a * N + p] != 0);
  if (any) atomicOr(&sh_has, 1);
  __syncthreads();
  int hasv = sh_has, tc = sh_tc;
  if (t == 0) {
    hasA[vi] = hasv;
    tcntA[vi] = tc;
    for (int q = 0; q < tc; q++) tlistA[vi * L + q] = sh_tl[q];
  }
  if (hasv) {
    for (int p = t; p < N; p += 256) {
      if (adj[(size_t)a * N + p] != 0) {
        unsigned bits = 0;
        for (int q = 0; q < tc; q++)
          if (adj[(size_t)p * N + sh_tl[q]] != 0) bits |= (1u << q);
        if (bits) {
          int slot = atomicAdd(&mcntA[vi], 1);
          mlistA[vi * MAXM + slot] = p;
          mmaskA[vi * MAXM + slot] = bits;
        }
      }
    }
  }
}

// ---------------------------------------------------------------------------
// k_msg: per-row CSR gather-sum of src_state, bf16-split into msg half of A
// (cols [256,512)).  One wave per row.
// ---------------------------------------------------------------------------
__global__ __launch_bounds__(256) void k_msg(
    const float* __restrict__ src_state, const int* __restrict__ row_ptr,
    const int* __restrict__ csr_src, ushort* __restrict__ Ahi,
    ushort* __restrict__ Alo) {
  int row = blockIdx.x * 4 + (threadIdx.x >> 6);
  int lane = threadIdx.x & 63;
  float4 acc = {0.f, 0.f, 0.f, 0.f};
  int e0 = row_ptr[row], e1 = row_ptr[row + 1];
  for (int e = e0; e < e1; e++) {
    const float4* r = (const float4*)(src_state + (size_t)csr_src[e] * D);
    float4 x = r[lane];
    acc.x += x.x; acc.y += x.y; acc.z += x.z; acc.w += x.w;
  }
  float vv[4] = {acc.x, acc.y, acc.z, acc.w};
  ushort h[4], l[4];
  for (int j = 0; j < 4; j++) {
    h[j] = bf16_rn(vv[j]);
    l[j] = bf16_rn(vv[j] - bf16_f(h[j]));
  }
  size_t o = (size_t)row * K2 + D + lane * 4;
  *(ushort4*)&Ahi[o] = make_ushort4(h[0], h[1], h[2], h[3]);
  *(ushort4*)&Alo[o] = make_ushort4(l[0], l[1], l[2], l[3]);
}

// ---------------------------------------------------------------------------
// k_gemm: next = relu(A @ Wcomb + b), A = [prev|msg] via bf16 3-product split
// (A1W1 + A1W2 + A2W1, fp32 accum).  Block = 64x64 tile, 4 waves 2x2, each
// wave 2x2 mfma_f32_16x16x32_bf16 tiles.  Epilogue writes next (fp32) and the
// self-half bf16 split of the NEXT app's A.
// Layouts [verified: m89 C/D col=lane&15,row=quad*4+reg; m120 A m=lane&15,
// k=quad*8+j; B dual: n=lane&15, k=quad*8+j].
// ---------------------------------------------------------------------------
#define AST 72   // LDS row stride (64 + 8 ushort pad = 144 B)
__global__ __launch_bounds__(256) void k_gemm(
    const ushort* __restrict__ Ahi, const ushort* __restrict__ Alo,
    const ushort* __restrict__ WtHi, const ushort* __restrict__ WtLo,
    const float* __restrict__ bias, float* __restrict__ next,
    ushort* __restrict__ NAhi, ushort* __restrict__ NAlo) {
  __shared__ __align__(16) ushort Ash[64][AST], Asl[64][AST];
  __shared__ __align__(16) ushort Wsh[64][AST], Wsl[64][AST];
  const int tid = threadIdx.x, wave = tid >> 6, lane = tid & 63;
  const int quad = lane >> 4, l16 = lane & 15;
  const int wr = wave >> 1, wc = wave & 1;
  const int m0 = blockIdx.x * 64, n0 = blockIdx.y * 64;

  f32x4 acc[2][2] = {};
  for (int kc = 0; kc < K2; kc += 64) {
    __syncthreads();
    for (int x = tid; x < 512; x += 256) {
      int r = x >> 3, cc = (x & 7) * 8;
      *(uint4*)&Ash[r][cc] = *(const uint4*)&Ahi[(size_t)(m0 + r) * K2 + kc + cc];
      *(uint4*)&Asl[r][cc] = *(const uint4*)&Alo[(size_t)(m0 + r) * K2 + kc + cc];
      *(uint4*)&Wsh[r][cc] = *(const uint4*)&WtHi[(size_t)(n0 + r) * K2 + kc + cc];
      *(uint4*)&Wsl[r][cc] = *(const uint4*)&WtLo[(size_t)(n0 + r) * K2 + kc + cc];
    }
    __syncthreads();
#pragma unroll
    for (int kf = 0; kf < 64; kf += 32) {
      int ko = kf + quad * 8;
      bf16x8 ah[2], al[2], wh[2], wl[2];
#pragma unroll
      for (int mt = 0; mt < 2; mt++) {
        ah[mt] = *(const bf16x8*)&Ash[wr * 32 + mt * 16 + l16][ko];
        al[mt] = *(const bf16x8*)&Asl[wr * 32 + mt * 16 + l16][ko];
      }
#pragma unroll
      for (int nt = 0; nt < 2; nt++) {
        wh[nt] = *(const bf16x8*)&Wsh[wc * 32 + nt * 16 + l16][ko];
        wl[nt] = *(const bf16x8*)&Wsl[wc * 32 + nt * 16 + l16][ko];
      }
#pragma unroll
      for (int mt = 0; mt < 2; mt++)
#pragma unroll
        for (int nt = 0; nt < 2; nt++) {
          acc[mt][nt] = __builtin_amdgcn_mfma_f32_16x16x32_bf16(ah[mt], wh[nt], acc[mt][nt], 0, 0, 0);
          acc[mt][nt] = __builtin_amdgcn_mfma_f32_16x16x32_bf16(ah[mt], wl[nt], acc[mt][nt], 0, 0, 0);
          acc[mt][nt] = __builtin_amdgcn_mfma_f32_16x16x32_bf16(al[mt], wh[nt], acc[mt][nt], 0, 0, 0);
        }
    }
  }
#pragma unroll
  for (int mt = 0; mt < 2; mt++)
#pragma unroll
    for (int nt = 0; nt < 2; nt++) {
      int col = n0 + wc * 32 + nt * 16 + l16;
      float bv = bias[col];
#pragma unroll
      for (int r = 0; r < 4; r++) {
        int row = m0 + wr * 32 + mt * 16 + quad * 4 + r;
        float v = fmaxf(acc[mt][nt][r] + bv, 0.f);
        next[(size_t)row * D + col] = v;
        ushort h = bf16_rn(v);
        NAhi[(size_t)row * K2 + col] = h;
        NAlo[(size_t)row * K2 + col] = bf16_rn(v - bf16_f(h));
      }
    }
}

// ---------------------------------------------------------------------------
// k_pi: column-parallel recurrence replay against stored encoder powers.
// Phases A+B fused (sum the freshly-written values); dst gather via bitmask.
// ---------------------------------------------------------------------------
__global__ __launch_bounds__(256) void k_pi(
    const float* __restrict__ states, float* __restrict__ pi,
    const int* __restrict__ variants, const int* __restrict__ hasA,
    const int* __restrict__ tlistA, const int* __restrict__ mcntA,
    const int* __restrict__ mlistA, const unsigned* __restrict__ mmaskA) {
  int v = blockIdx.x / 3, cg = blockIdx.x % 3;
  int c = cg * 256 + threadIdx.x;
  float* piv = pi + (size_t)v * N * C;
  float summary = 0.f;
  int k = 0;
  for (int i = 0; i < L; i++) {
    int vi = v * L + i;
    int kk = k < NSTATE ? k : NSTATE - 1;
    const float* embS = states + (size_t)kk * N * D;
    int a = variants[vi];
    int mc = mcntA[vi];
    float embA = (cg == 1) ? embS[(size_t)a * D + (c - D)] : 0.f;
    float sacc = 0.f;
    for (int m = 0; m < mc; m++) {
      int p = mlistA[vi * MAXM + m];
      float catv;
      if (cg == 0) {
        catv = embS[(size_t)p * D + c];
      } else if (cg == 1) {
        catv = embA;
      } else {
        catv = 0.f;
        unsigned b = mmaskA[vi * MAXM + m];
        while (b) {
          int q = __ffs(b) - 1;
          b &= b - 1;
          catv += embS[(size_t)tlistA[vi * L + q] * D + (c - 2 * D)];
        }
      }
      size_t idx = (size_t)p * C + c;
      float nv = piv[idx] + catv;
      piv[idx] = nv;
      sacc += nv;
    }
    summary += sacc;
    for (int m = 0; m < mc; m++) {
      size_t idx = (size_t)mlistA[vi * MAXM + m] * C + c;
      piv[idx] += summary;
    }
    if (hasA[vi]) k++;
  }
}

// ---------------------------------------------------------------------------
__global__ void k_out(const float* __restrict__ pi, float* __restrict__ out) {
  size_t i = (size_t)blockIdx.x * 256 + threadIdx.x;
  size_t n4 = (size_t)N * C / 4;
  if (i < n4) {
    float4 a = ((const float4*)pi)[i];
    float4 b = ((const float4*)(pi + (size_t)N * C))[i];
    float4 o = {a.x + b.x, a.y + b.y, a.z + b.z, a.w + b.w};
    ((float4*)out)[i] = o;
  }
}

// ---------------------------------------------------------------------------
extern "C" void kernel_launch(void* const* d_in, const int* in_sizes, int n_in,
                              void* d_out, int out_size, void* d_ws, size_t ws_size,
                              hipStream_t stream) {
  const float* emb      = (const float*)d_in[0];
  const float* Ws       = (const float*)d_in[1];
  const float* Wn       = (const float*)d_in[2];
  const float* bias     = (const float*)d_in[3];
  const int*   variants = (const int*)d_in[4];
  const int*   adj      = (const int*)d_in[5];
  const int*   ei       = (const int*)d_in[6];
  const int    E        = in_sizes[6] / 2;

  char* base = (char*)d_ws;
  float* states = (float*)base;            base += (size_t)NSTATE * N * D * 4;
  float* pi     = (float*)base;            base += (size_t)V * N * C * 4;
  ushort* WtHi  = (ushort*)base;           base += (size_t)D * K2 * 2;
  ushort* WtLo  = (ushort*)base;           base += (size_t)D * K2 * 2;
  ushort* Ahi0  = (ushort*)base;           base += (size_t)N * K2 * 2;
  ushort* Alo0  = (ushort*)base;           base += (size_t)N * K2 * 2;
  ushort* Ahi1  = (ushort*)base;           base += (size_t)N * K2 * 2;
  ushort* Alo1  = (ushort*)base;           base += (size_t)N * K2 * 2;
  int* row_ptr  = (int*)base;              base += (N + 1) * 4;
  int* fillpos  = (int*)base;              base += N * 4;
  int* csr_src  = (int*)base;              base += (size_t)E * 4;
  int* hasA     = (int*)base;              base += V * L * 4;
  int* tcntA    = (int*)base;              base += V * L * 4;
  int* tlistA   = (int*)base;              base += V * L * L * 4;
  int* mcntA    = (int*)base;              base += V * L * 4;
  int* mlistA   = (int*)base;              base += (size_t)V * L * MAXM * 4;
  unsigned* mmaskA = (unsigned*)base;      base += (size_t)V * L * MAXM * 4;

  ushort* AH[2] = {Ahi0, Ahi1};
  ushort* AL[2] = {Alo0, Alo1};

  k_init<<<512, 256, 0, stream>>>(emb, Ws, Wn, states, WtHi, WtLo,
                                  AH[0], AL[0], pi, fillpos, mcntA);
  k_deg<<<(E + 255) / 256, 256, 0, stream>>>(ei, fillpos, E);
  k_scan<<<1, 256, 0, stream>>>(fillpos, row_ptr);
  k_fill<<<(E + 255) / 256, 256, 0, stream>>>(ei, fillpos, csr_src, E);
  k_meta<<<V * L, 256, 0, stream>>>(adj, variants, hasA, tcntA, tlistA,
                                    mcntA, mlistA, mmaskA);
  k_msg<<<N / 4, 256, 0, stream>>>(states, row_ptr, csr_src, AH[0], AL[0]);
  for (int s = 0; s < NSTATE - 1; s++) {
    int cur = s & 1, nxt = cur ^ 1;
    k_gemm<<<dim3(N / 64, D / 64), 256, 0, stream>>>(
        AH[cur], AL[cur], WtHi, WtLo, bias,
        states + (size_t)(s + 1) * N * D, AH[nxt], AL[nxt]);
    if (s < NSTATE - 2)
      k_msg<<<N / 4, 256, 0, stream>>>(states + (size_t)(s + 1) * N * D,
                                       row_ptr, csr_src, AH[nxt], AL[nxt]);
  }
  k_pi<<<V * 3, 256, 0, stream>>>(states, pi, variants, hasA, tlistA,
                                  mcntA, mlistA, mmaskA);
  k_out<<<(N * C / 4 + 255) / 256, 256, 0, stream>>>(pi, (float*)d_out);
}